// Round 12
// baseline (362.858 us; speedup 1.0000x reference)
//
#include <hip/hip_runtime.h>
#include <stdint.h>

// ---------- types ----------
typedef __attribute__((ext_vector_type(8))) short short8;
typedef __attribute__((ext_vector_type(4))) short short4v;
typedef __attribute__((ext_vector_type(8))) __bf16 bf16x8;
typedef __attribute__((ext_vector_type(4))) float f32x4;

#define SEQ 2048
#define DMODEL 768
#define NHEAD 12
#define HD 64
#define NBATCH 4

// softmax scale folded into Q at QKV-projection epilogue: 1/sqrt(64) * log2(e)
#define QSCALE 0.18033688011112042f

__device__ __forceinline__ float bf2f(unsigned short u) {
    return __uint_as_float(((unsigned int)u) << 16);
}
__device__ __forceinline__ unsigned short f2bf(float f) {
    unsigned int u = __float_as_uint(f);
    u += 0x7fffu + ((u >> 16) & 1u);   // round-to-nearest-even
    return (unsigned short)(u >> 16);
}
// native f32 -> bf16 (RNE), lets the compiler emit v_cvt_pk_bf16_f32
__device__ __forceinline__ unsigned short f2bfn(float f) {
    union { __bf16 h; unsigned short u; } cv;
    cv.h = (__bf16)f;
    return cv.u;
}
__device__ __forceinline__ short8 cvt8(float4 a, float4 b) {
    short8 r;
    r[0] = (short)f2bf(a.x); r[1] = (short)f2bf(a.y);
    r[2] = (short)f2bf(a.z); r[3] = (short)f2bf(a.w);
    r[4] = (short)f2bf(b.x); r[5] = (short)f2bf(b.y);
    r[6] = (short)f2bf(b.z); r[7] = (short)f2bf(b.w);
    return r;
}
__device__ __forceinline__ f32x4 mfma16(short8 a, short8 b, f32x4 c) {
    return __builtin_amdgcn_mfma_f32_16x16x32_bf16(
        __builtin_bit_cast(bf16x8, a), __builtin_bit_cast(bf16x8, b), c, 0, 0, 0);
}
// 16x16x16 bf16 MFMA: A/B = 4 bf16 (2 VGPR). Lane layout:
//   A[m=lane&15][k=(lane>>4)*4+j], B[n=lane&15][k=(lane>>4)*4+j],
//   D[m=(lane>>4)*4+r][n=lane&15]
__device__ __forceinline__ f32x4 mfma16k16(short4v a, short4v b, f32x4 c) {
#if __has_builtin(__builtin_amdgcn_mfma_f32_16x16x16bf16_1k)
    return __builtin_amdgcn_mfma_f32_16x16x16bf16_1k(a, b, c, 0, 0, 0);
#else
    asm("v_mfma_f32_16x16x16_bf16 %0, %1, %2, %0" : "+v"(c) : "v"(a), "v"(b));
    return c;
#endif
}
// async global->LDS, 16B per lane; dst = wave-uniform base + lane*16
__device__ __forceinline__ void gload16(const unsigned short* g, unsigned short* l) {
    __builtin_amdgcn_global_load_lds(
        (const __attribute__((address_space(1))) unsigned int*)g,
        (__attribute__((address_space(3))) unsigned int*)l, 16, 0, 0);
}

// ---------- runtime dtype detection (1 = fp32, 0 = bf16), parallel ----------
__global__ void detect_k(const unsigned short* x, const unsigned short* w1,
                         const unsigned short* b1, const unsigned short* w2,
                         const unsigned short* b2, int* flags) {
    const int w = threadIdx.x >> 6, l = threadIdx.x & 63;
    if (w >= 5) return;
    const unsigned short* ptrs[5] = {x, w1, b1, w2, b2};
    const unsigned short* p = ptrs[w];
    float mx = 0.f;
    for (int j = l; j < 1024; j += 64) {
        float v = fabsf(bf2f(p[j]));
        if (!(v <= 1e30f)) v = 1e31f;
        if (v > mx) mx = v;
    }
#pragma unroll
    for (int off = 1; off < 64; off <<= 1) mx = fmaxf(mx, __shfl_xor(mx, off, 64));
    if (l == 0) flags[w] = (mx > 1e3f) ? 1 : 0;
}

// ---------- X -> bf16 (convert or copy), 8 elems/thread ----------
__global__ __launch_bounds__(256) void cvt_x(
    const float* __restrict__ Xf, const unsigned short* __restrict__ Xh,
    unsigned short* __restrict__ Xb, const int* __restrict__ flags, int n8) {
    int i = blockIdx.x * 256 + threadIdx.x;
    if (i >= n8) return;
    if (flags[0]) {
        float4 a = ((const float4*)Xf)[(size_t)i * 2];
        float4 b = ((const float4*)Xf)[(size_t)i * 2 + 1];
        *(short8*)&Xb[(size_t)i * 8] = cvt8(a, b);
    } else {
        ((uint4*)Xb)[i] = ((const uint4*)Xh)[i];
    }
}

// ---------- tiled transpose+convert W[R][C] -> bf16 Wt[C][R] (both weights) ----------
__device__ __forceinline__ void wt_body(
    unsigned short (*tile)[65], const float* __restrict__ Wf,
    const unsigned short* __restrict__ Wh, unsigned short* __restrict__ Wt,
    int R, int C, bool f32, int bx, int by, int t) {

    const int c0 = bx * 64, r0 = by * 64;
    const int ri = t >> 2, cj = (t & 3) * 16;

    if (f32) {
#pragma unroll
        for (int u = 0; u < 4; u++) {
            float4 v = *(const float4*)&Wf[(size_t)(r0 + ri) * C + c0 + cj + u * 4];
            tile[ri][cj + u * 4 + 0] = f2bf(v.x);
            tile[ri][cj + u * 4 + 1] = f2bf(v.y);
            tile[ri][cj + u * 4 + 2] = f2bf(v.z);
            tile[ri][cj + u * 4 + 3] = f2bf(v.w);
        }
    } else {
        uint4 a = *(const uint4*)&Wh[(size_t)(r0 + ri) * C + c0 + cj];
        uint4 b = *(const uint4*)&Wh[(size_t)(r0 + ri) * C + c0 + cj + 8];
        *(uint4*)&tile[ri][cj] = a;
        *(uint4*)&tile[ri][cj + 8] = b;
    }
    __syncthreads();

    const int ci = t >> 2, rj = (t & 3) * 16;
    unsigned short tmp[16];
#pragma unroll
    for (int u = 0; u < 16; u++) tmp[u] = tile[rj + u][ci];
    *(uint4*)&Wt[(size_t)(c0 + ci) * R + r0 + rj]     = *(uint4*)&tmp[0];
    *(uint4*)&Wt[(size_t)(c0 + ci) * R + r0 + rj + 8] = *(uint4*)&tmp[8];
}

// grid (36, 24): y<12 -> W1 [768][2304]; y>=12 (x<12) -> W2 [768][768]
__global__ __launch_bounds__(256) void convert_wt_both(
    const float* __restrict__ Wf1, const unsigned short* __restrict__ Wh1,
    unsigned short* __restrict__ Wt1,
    const float* __restrict__ Wf2, const unsigned short* __restrict__ Wh2,
    unsigned short* __restrict__ Wt2, const int* __restrict__ flags) {

    __shared__ unsigned short tile[64][65];
    const int t = threadIdx.x;
    if (blockIdx.y < 12) {
        wt_body(tile, Wf1, Wh1, Wt1, 768, 2304, flags[1] != 0,
                (int)blockIdx.x, (int)blockIdx.y, t);
    } else {
        if (blockIdx.x >= 12) return;
        wt_body(tile, Wf2, Wh2, Wt2, 768, 768, flags[3] != 0,
                (int)blockIdx.x, (int)blockIdx.y - 12, t);
    }
}

// ---------- MFMA GEMM: C[M,N] = A[M,K] @ Bt[N,K]^T + bias ----------
// r8 configuration (best measured): BK=64 per K-step (two 32-wide halves in
// LDS [2][128][32]) -> 32 MFMA per barrier pair; plain __syncthreads drains.
// At 32 KB LDS + (256,4) = 16 waves/CU, implicit wave-level overlap (m114)
// covers the drains better than the explicit 2/3-buffer pipelines tried in
// r9/r10 (both regressed: fewer waves / more sync points).
// aFidx<0: A bf16 via global_load_lds. aFidx>=0 + fp32 flag: register-stage+cvt
// (uncoalesced; cold path only -- r7 measured 108us on the hot path).
// mode 0: scatter QKV -> Q[BH,S,hd] (pre-scaled by QSCALE), K[BH,S,hd],
//         Vt[BH,hd,S] (bf16)                                          (N=2304)
// mode 1: store fp32 to outf[M,DMODEL]                                (N=768)
// XCD-aware bijective block swizzle for L2 locality.
__global__ __launch_bounds__(256, 4) void gemm_bt(
    const float* __restrict__ Af, const unsigned short* __restrict__ Ah,
    const unsigned short* __restrict__ Bt,
    const float* __restrict__ biasf, const unsigned short* __restrict__ biash,
    int K, int mode, const int* __restrict__ flags, int aFidx, int bFidx,
    unsigned short* __restrict__ out0, unsigned short* __restrict__ out1,
    unsigned short* __restrict__ out2, float* __restrict__ outf) {

    __shared__ __align__(16) unsigned short As[2][128][32];
    __shared__ __align__(16) unsigned short Bs[2][128][32];

    int bx = blockIdx.x, by = blockIdx.y;
    {
        const int nwg = (int)(gridDim.x * gridDim.y);
        if ((nwg & 7) == 0) {
            int bid = by * gridDim.x + bx;
            const int cpx = nwg >> 3;
            bid = (bid & 7) * cpx + (bid >> 3);
            bx = bid % gridDim.x;
            by = bid / gridDim.x;
        }
    }
    const int mBase = by * 128;
    const int nBase = bx * 128;
    const int t = threadIdx.x;
    const int w = t >> 6, l = t & 63, lr = l & 15, lk = l >> 4;
    const int wr = w >> 1, wc = w & 1;

    const bool af32 = (aFidx >= 0) && (flags[aFidx] != 0);
    const bool bf32 = flags[bFidx] != 0;

    f32x4 zero = {0.f, 0.f, 0.f, 0.f};
    f32x4 acc[4][4];
#pragma unroll
    for (int i = 0; i < 4; i++)
#pragma unroll
        for (int j = 0; j < 4; j++) acc[i][j] = zero;

    const int arow2 = t >> 1;          // af32 path: row 0..127
    const int ha32 = t & 1;            // af32 path: k-half
    const float* Afp = Af + (size_t)mBase * K;
    const unsigned short* Ahp = Ah + (size_t)mBase * K;
    const unsigned short* Bp = Bt + (size_t)nBase * K;

    unsigned short* BsF = &Bs[0][0][0];
    unsigned short* AsF = &As[0][0][0];

    for (int k0 = 0; k0 < K; k0 += 64) {
        // stage B: 1024 granules of 16B; LDS granule c == [ha][row][g2]
#pragma unroll
        for (int q = 0; q < 4; q++) {
            const int c = q * 256 + t;
            const int row = (c >> 2) & 127;
            const int ha = c >> 9;
            const int g2 = c & 3;
            gload16(&Bp[(size_t)row * K + k0 + ha * 32 + g2 * 8],
                    BsF + (size_t)(q * 256 + w * 64) * 8);
        }
        if (af32) {
#pragma unroll
            for (int u = 0; u < 4; u++) {
                float4 f0 = *(const float4*)&Afp[(size_t)arow2 * K + k0 + ha32 * 32 + u * 8];
                float4 f1 = *(const float4*)&Afp[(size_t)arow2 * K + k0 + ha32 * 32 + u * 8 + 4];
                *(short8*)&As[ha32][arow2][u * 8] = cvt8(f0, f1);
            }
        } else {
#pragma unroll
            for (int q = 0; q < 4; q++) {
                const int c = q * 256 + t;
                const int row = (c >> 2) & 127;
                const int ha = c >> 9;
                const int g2 = c & 3;
                gload16(&Ahp[(size_t)row * K + k0 + ha * 32 + g2 * 8],
                        AsF + (size_t)(q * 256 + w * 64) * 8);
            }
        }
        __syncthreads();

#pragma unroll
        for (int ha = 0; ha < 2; ha++) {
            short8 a[4], b[4];
#pragma unroll
            for (int i = 0; i < 4; i++)
                a[i] = *(const short8*)&As[ha][wr * 64 + i * 16 + lr][lk * 8];
#pragma unroll
            for (int j = 0; j < 4; j++)
                b[j] = *(const short8*)&Bs[ha][wc * 64 + j * 16 + lr][lk * 8];
#pragma unroll
            for (int i = 0; i < 4; i++)
#pragma unroll
                for (int j = 0; j < 4; j++) acc[i][j] = mfma16(a[i], b[j], acc[i][j]);
        }
        __syncthreads();
    }

    // epilogue: C/D layout col=lane&15, row=quad*4+r
#pragma unroll
    for (int j = 0; j < 4; j++) {
        int col = nBase + wc * 64 + j * 16 + lr;
        float bv = bf32 ? biasf[col] : bf2f(biash[col]);
        if (mode == 0 && col >= 1536) {
            // Vt[h][d][s]: 4 consecutive s -> one 8B store
            int c2 = col - 1536;
            int h = c2 >> 6, d = c2 & 63;
#pragma unroll
            for (int i = 0; i < 4; i++) {
                int row0 = mBase + wr * 64 + i * 16 + lk * 4;
                int bb = row0 >> 11, s0 = row0 & 2047;
                short4v hv4;
#pragma unroll
                for (int r = 0; r < 4; r++) hv4[r] = (short)f2bf(acc[i][j][r] + bv);
                *(short4v*)&out2[(((size_t)(bb * NHEAD + h)) * HD + d) * SEQ + s0] = hv4;
            }
        } else {
#pragma unroll
            for (int i = 0; i < 4; i++) {
                int row0 = mBase + wr * 64 + i * 16 + lk * 4;
#pragma unroll
                for (int r = 0; r < 4; r++) {
                    int row = row0 + r;
                    float fv = acc[i][j][r] + bv;
                    if (mode == 0) {
                        int bb = row >> 11;
                        int s  = row & 2047;
                        if (col < 768) {
                            // Q: fold softmax scale here (saves VALU in flash)
                            int h = col >> 6, d = col & 63;
                            out0[(((size_t)(bb * NHEAD + h)) * SEQ + s) * HD + d] =
                                f2bf(fv * QSCALE);
                        } else {
                            int c2 = col - 768;
                            int h = c2 >> 6, d = c2 & 63;
                            out1[(((size_t)(bb * NHEAD + h)) * SEQ + s) * HD + d] =
                                f2bf(fv);
                        }
                    } else {
                        outf[(size_t)row * DMODEL + col] = fv;
                    }
                }
            }
        }
    }
}

// ---------- flash attention v9: 2-buffer (32 KB LDS) + 4 blocks/CU ----------
// r10's x3-unrolled variant spilled (WRITE_SIZE 27->214 MB): reverted to the
// rolled v7 body. Change vs r8: LDS 48->32 KB (2 buffers, prefetch-1) and
// __launch_bounds__(256,4). flash is latency-bound with no saturated pipe
// (MFMA 21%, VALU 54%, HBM 11%); VGPR 84 <= 128 allows 16 waves/CU, and the
// old (256,3) declaration was itself the residency cap. +33% TLP covers the
// per-iteration drain better than the 3-buffer counted-vmcnt did (r5: +1.7us).
#define STAGE(buf, tile) do {                                                  \
    _Pragma("unroll")                                                          \
    for (int q_ = 0; q_ < 2; ++q_) {                                           \
        const int c_ = w * 128 + q_ * 64 + l;                                  \
        const int row_ = c_ >> 3;                                              \
        const int ch_ = (c_ & 7) ^ (row_ & 7);                                 \
        gload16(&Kp[(size_t)((tile) * 64 + row_) * HD + ch_ * 8],              \
                &Ks[buf][(w * 128 + q_ * 64) * 8]);                            \
        gload16(&Vp[(size_t)row_ * SEQ + (tile) * 64 + ch_ * 8],               \
                &Vs[buf][(w * 128 + q_ * 64) * 8]);                            \
    }                                                                          \
} while (0)

__global__ __launch_bounds__(256, 4) void flash_attn(
    const unsigned short* __restrict__ Q, const unsigned short* __restrict__ Km,
    const unsigned short* __restrict__ Vt, unsigned short* __restrict__ Oatt) {

    const int h  = blockIdx.x;
    const int px = (7 * blockIdx.y + blockIdx.x + blockIdx.z) & 15;  // scrambled pair idx
    const int b  = blockIdx.z;
    const int bh = b * NHEAD + h;
    const int qtA = 31 - px;          // heavy q-tile (16..31)
    const int qtB = px;               // light q-tile (0..15)
    const int t = threadIdx.x, w = t >> 6, l = t & 63, lr = l & 15, lk = l >> 4;
    const int qbA = qtA * 64 + w * 16;
    const int qbB = qtB * 64 + w * 16;

    const unsigned short* Qp = Q + (size_t)bh * SEQ * HD;
    const unsigned short* Kp = Km + (size_t)bh * SEQ * HD;
    const unsigned short* Vp = Vt + (size_t)bh * HD * SEQ;

    __shared__ __align__(16) unsigned short Ks[2][4096];
    __shared__ __align__(16) unsigned short Vs[2][4096];

    short8 qA0 = *(const short8*)&Qp[(size_t)(qbA + lr) * HD + lk * 8];
    short8 qA1 = *(const short8*)&Qp[(size_t)(qbA + lr) * HD + 32 + lk * 8];
    short8 qB0 = *(const short8*)&Qp[(size_t)(qbB + lr) * HD + lk * 8];
    short8 qB1 = *(const short8*)&Qp[(size_t)(qbB + lr) * HD + 32 + lk * 8];

    f32x4 zero = {0.f, 0.f, 0.f, 0.f};
    f32x4 oA[4], oB[4];
    float lsumA = 0.f, lsumB = 0.f;
#pragma unroll
    for (int dt = 0; dt < 4; dt++) { oA[dt] = zero; oB[dt] = zero; }

    // prologue: stage tile 0
    STAGE(0, 0);
    asm volatile("s_waitcnt vmcnt(0)" ::: "memory");
    __builtin_amdgcn_s_barrier();

    int cur = 0;
    for (int kt = 0; kt <= qtA; ++kt) {
        if (kt < qtA) STAGE(cur ^ 1, kt + 1);   // prefetch overlaps compute
        const bool doB = (kt <= qtB);

        // ---- QK^T (swapped: K as A, Q as B), K fragments read once ----
        f32x4 s0[4], s1[4];
        __builtin_amdgcn_s_setprio(1);
#pragma unroll
        for (int ct = 0; ct < 4; ct++) {
            const int row = ct * 16 + lr, sw = row & 7;
            short8 k0 = *(const short8*)&Ks[cur][(row * 8 + (lk ^ sw)) * 8];
            short8 k1 = *(const short8*)&Ks[cur][(row * 8 + ((4 | lk) ^ sw)) * 8];
            s0[ct] = mfma16(k0, qA0, zero);
            s0[ct] = mfma16(k1, qA1, s0[ct]);
            if (doB) {
                s1[ct] = mfma16(k0, qB0, zero);
                s1[ct] = mfma16(k1, qB1, s1[ct]);
            }
        }
        __builtin_amdgcn_s_setprio(0);

        // ---- V fragments for 16x16x16 PV: B[n=d=lr][k=key=ct*16+lk*4+j] ----
        short4v vf[4][4];
#pragma unroll
        for (int dt = 0; dt < 4; dt++) {
            const int row = dt * 16 + lr;          // d index
            const int sw = row & 7;
#pragma unroll
            for (int ct = 0; ct < 4; ct++) {
                const int g = 2 * ct + (lk >> 1);  // 16B source granule
                const int hh = lk & 1;             // 8B half within granule
                vf[dt][ct] = *(const short4v*)&Vs[cur][(row * 8 + (g ^ sw)) * 8 + hh * 4];
            }
        }

        // ---- strip A: softmax in-register (Q pre-scaled -> just exp2), pack, PV ----
        short4v paA[4];
        {
            float p[4][4];
#pragma unroll
            for (int ct = 0; ct < 4; ct++)
#pragma unroll
                for (int r = 0; r < 4; r++) p[ct][r] = exp2f(s0[ct][r]);
            if (kt == qtA) {   // causal mask: zero after exp2
                const int qrow = qbA + lr;
#pragma unroll
                for (int ct = 0; ct < 4; ct++)
#pragma unroll
                    for (int r = 0; r < 4; r++) {
                        const int key = kt * 64 + ct * 16 + lk * 4 + r;
                        if (key > qrow) p[ct][r] = 0.0f;
                    }
            }
#pragma unroll
            for (int ct = 0; ct < 4; ct++)
                lsumA += (p[ct][0] + p[ct][1]) + (p[ct][2] + p[ct][3]);
#pragma unroll
            for (int ct = 0; ct < 4; ct++) {
                short4v pk;
#pragma unroll
                for (int r = 0; r < 4; r++) pk[r] = (short)f2bfn(p[ct][r]);
                paA[ct] = pk;
            }
        }
        __builtin_amdgcn_s_setprio(1);
#pragma unroll
        for (int dt = 0; dt < 4; dt++)
#pragma unroll
            for (int ct = 0; ct < 4; ct++)
                oA[dt] = mfma16k16(paA[ct], vf[dt][ct], oA[dt]);
        __builtin_amdgcn_s_setprio(0);

        // ---- strip B ----
        if (doB) {
            short4v paB[4];
            float p[4][4];
#pragma unroll
            for (int ct = 0; ct < 4; ct++)
#pragma unroll
                for (int r = 0; r < 4; r++) p[ct][r] = exp2f(s1[ct][r]);
            if (kt == qtB) {
                const int qrow = qbB + lr;
#pragma unroll
                for (int ct = 0; ct < 4; ct++)
#pragma unroll
                    for (int r = 0; r < 4; r++) {
                        const int key = kt * 64 + ct * 16 + lk * 4 + r;
                        if (key > qrow) p[ct][r] = 0.0f;
                    }
            }
#pragma unroll
            for (int ct = 0; ct < 4; ct++)
                lsumB += (p[ct][0] + p[ct][1]) + (p[ct][2] + p[ct][3]);
#pragma unroll
            for (int ct = 0; ct < 4; ct++) {
                short4v pk;
#pragma unroll
                for (int r = 0; r < 4; r++) pk[r] = (short)f2bfn(p[ct][r]);
                paB[ct] = pk;
            }
            __builtin_amdgcn_s_setprio(1);
#pragma unroll
            for (int dt = 0; dt < 4; dt++)
#pragma unroll
                for (int ct = 0; ct < 4; ct++)
                    oB[dt] = mfma16k16(paB[ct], vf[dt][ct], oB[dt]);
            __builtin_amdgcn_s_setprio(0);
        }

        // ---- barrier: prefetched tile kt+1 must have landed ----
        if (kt < qtA) {
            asm volatile("s_waitcnt vmcnt(0)" ::: "memory");
            __builtin_amdgcn_s_barrier();
        }
        cur ^= 1;
    }

    // row-sum lives per lane at q=lr; reduce across the 4 lk groups
    lsumA += __shfl_xor(lsumA, 16, 64);
    lsumA += __shfl_xor(lsumA, 32, 64);
    lsumB += __shfl_xor(lsumB, 16, 64);
    lsumB += __shfl_xor(lsumB, 32, 64);

#pragma unroll
    for (int r = 0; r < 4; r++) {
        const float invA = 1.0f / __shfl(lsumA, lk * 4 + r, 64);
        const float invB = 1.0f / __shfl(lsumB, lk * 4 + r, 64);
        const int rowA = qbA + lk * 4 + r;
        const int rowB = qbB + lk * 4 + r;
#pragma unroll
        for (int dt = 0; dt < 4; dt++) {
            Oatt[((size_t)(b * SEQ) + rowA) * DMODEL + h * HD + dt * 16 + lr] =
                f2bfn(oA[dt][r] * invA);
            Oatt[((size_t)(b * SEQ) + rowB) * DMODEL + h * HD + dt * 16 + lr] =
                f2bfn(oB[dt][r] * invB);
        }
    }
}

extern "C" void kernel_launch(void* const* d_in, const int* in_sizes, int n_in,
                              void* d_out, int out_size, void* d_ws, size_t ws_size,
                              hipStream_t stream) {
    const void *X = d_in[0], *W1 = d_in[1], *b1 = d_in[2], *W2 = d_in[3], *b2 = d_in[4];
    for (int i = 0; i < n_in; i++) {
        switch (in_sizes[i]) {
            case NBATCH * SEQ * DMODEL: X  = d_in[i]; break;
            case DMODEL * 3 * DMODEL:   W1 = d_in[i]; break;
            case 3 * DMODEL:            b1 = d_in[i]; break;
            case DMODEL * DMODEL:       W2 = d_in[i]; break;
            case DMODEL:                b2 = d_in[i]; break;
        }
    }
    float* out = (float*)d_out;

    int* flags = (int*)d_ws;
    unsigned short* base = (unsigned short*)d_ws + 64;
    unsigned short* Wt1 = base;                                 // [2304][768]
    unsigned short* Wt2 = Wt1 + (size_t)2304 * 768;             // [768][768]

    const size_t headElems = (size_t)NHEAD * SEQ * HD;          // 1.57M / batch
    const size_t xElems = (size_t)NBATCH * SEQ * DMODEL;        // 6.29M
    const size_t fixedElems = 64 + (size_t)2304 * 768 + (size_t)768 * 768;
    const size_t mergedNeed = (fixedElems + xElems + 4 * NBATCH * headElems) * 2 + 1024;
    const bool merged = ws_size >= mergedNeed;

    detect_k<<<1, 320, 0, stream>>>(
        (const unsigned short*)X, (const unsigned short*)W1,
        (const unsigned short*)b1, (const unsigned short*)W2,
        (const unsigned short*)b2, flags);

    convert_wt_both<<<dim3(36, 24), 256, 0, stream>>>(
        (const float*)W1, (const unsigned short*)W1, Wt1,
        (const float*)W2, (const unsigned short*)W2, Wt2, flags);

    if (merged) {
        unsigned short* Xb  = Wt2 + (size_t)768 * 768;          // [8192][768] bf16
        unsigned short* Qw  = Xb + xElems;
        unsigned short* Kw  = Qw + (size_t)NBATCH * headElems;
        unsigned short* Vtw = Kw + (size_t)NBATCH * headElems;
        unsigned short* Aw  = Vtw + (size_t)NBATCH * headElems;

        // coalesced X -> bf16 pass (in-gemm fp32 A path measured 108us in r7:
        // uncoalesced loads + LDS write conflicts; separate pass is better)
        cvt_x<<<(int)((xElems / 8 + 255) / 256), 256, 0, stream>>>(
            (const float*)X, (const unsigned short*)X, Xb, flags, (int)(xElems / 8));

        gemm_bt<<<dim3(2304 / 128, NBATCH * SEQ / 128), 256, 0, stream>>>(
            nullptr, Xb, Wt1,
            (const float*)b1, (const unsigned short*)b1,
            DMODEL, 0, flags, -1, 2, Qw, Kw, Vtw, nullptr);

        flash_attn<<<dim3(NHEAD, 16, NBATCH), 256, 0, stream>>>(Qw, Kw, Vtw, Aw);

        gemm_bt<<<dim3(768 / 128, NBATCH * SEQ / 128), 256, 0, stream>>>(
            nullptr, Aw, Wt2,
            (const float*)b2, (const unsigned short*)b2,
            DMODEL, 1, flags, -1, 4, nullptr, nullptr, nullptr, out);
    } else {
        unsigned short* Qw  = Wt2 + (size_t)768 * 768;
        unsigned short* Kw  = Qw + headElems;
        unsigned short* Vtw = Kw + headElems;
        unsigned short* Aw  = Vtw + headElems;
        for (int batch = 0; batch < NBATCH; ++batch) {
            const size_t xoff = (size_t)batch * SEQ * DMODEL;

            gemm_bt<<<dim3(2304 / 128, SEQ / 128), 256, 0, stream>>>(
                (const float*)X + xoff, (const unsigned short*)X + xoff, Wt1,
                (const float*)b1, (const unsigned short*)b1,
                DMODEL, 0, flags, 0, 2, Qw, Kw, Vtw, nullptr);

            flash_attn<<<dim3(NHEAD, 16, 1), 256, 0, stream>>>(Qw, Kw, Vtw, Aw);

            gemm_bt<<<dim3(768 / 128, SEQ / 128), 256, 0, stream>>>(
                nullptr, Aw, Wt2,
                (const float*)b2, (const unsigned short*)b2,
                DMODEL, 1, flags, -1, 4, nullptr, nullptr, nullptr, out + xoff);
        }
    }
}

// Round 14
// 224.651 us; speedup vs baseline: 1.6152x; 1.6152x over previous
//
#include <hip/hip_runtime.h>
#include <stdint.h>

// ---------- types ----------
typedef __attribute__((ext_vector_type(8))) short short8;
typedef __attribute__((ext_vector_type(4))) short short4v;
typedef __attribute__((ext_vector_type(8))) __bf16 bf16x8;
typedef __attribute__((ext_vector_type(4))) float f32x4;

#define SEQ 2048
#define DMODEL 768
#define NHEAD 12
#define HD 64
#define NBATCH 4

// softmax scale folded into Q at QKV-projection epilogue: 1/sqrt(64) * log2(e)
#define QSCALE 0.18033688011112042f

__device__ __forceinline__ float bf2f(unsigned short u) {
    return __uint_as_float(((unsigned int)u) << 16);
}
__device__ __forceinline__ unsigned short f2bf(float f) {
    unsigned int u = __float_as_uint(f);
    u += 0x7fffu + ((u >> 16) & 1u);   // round-to-nearest-even
    return (unsigned short)(u >> 16);
}
// native f32 -> bf16 (RNE), lets the compiler emit v_cvt_pk_bf16_f32
__device__ __forceinline__ unsigned short f2bfn(float f) {
    union { __bf16 h; unsigned short u; } cv;
    cv.h = (__bf16)f;
    return cv.u;
}
__device__ __forceinline__ short8 cvt8(float4 a, float4 b) {
    short8 r;
    r[0] = (short)f2bf(a.x); r[1] = (short)f2bf(a.y);
    r[2] = (short)f2bf(a.z); r[3] = (short)f2bf(a.w);
    r[4] = (short)f2bf(b.x); r[5] = (short)f2bf(b.y);
    r[6] = (short)f2bf(b.z); r[7] = (short)f2bf(b.w);
    return r;
}
__device__ __forceinline__ f32x4 mfma16(short8 a, short8 b, f32x4 c) {
    return __builtin_amdgcn_mfma_f32_16x16x32_bf16(
        __builtin_bit_cast(bf16x8, a), __builtin_bit_cast(bf16x8, b), c, 0, 0, 0);
}
// 16x16x16 bf16 MFMA: A/B = 4 bf16 (2 VGPR). Lane layout:
//   A[m=lane&15][k=(lane>>4)*4+j], B[n=lane&15][k=(lane>>4)*4+j],
//   D[m=(lane>>4)*4+r][n=lane&15]
__device__ __forceinline__ f32x4 mfma16k16(short4v a, short4v b, f32x4 c) {
#if __has_builtin(__builtin_amdgcn_mfma_f32_16x16x16bf16_1k)
    return __builtin_amdgcn_mfma_f32_16x16x16bf16_1k(a, b, c, 0, 0, 0);
#else
    asm("v_mfma_f32_16x16x16_bf16 %0, %1, %2, %0" : "+v"(c) : "v"(a), "v"(b));
    return c;
#endif
}
// async global->LDS, 16B per lane; dst = wave-uniform base + lane*16
__device__ __forceinline__ void gload16(const unsigned short* g, unsigned short* l) {
    __builtin_amdgcn_global_load_lds(
        (const __attribute__((address_space(1))) unsigned int*)g,
        (__attribute__((address_space(3))) unsigned int*)l, 16, 0, 0);
}

// ---------- runtime dtype detection (1 = fp32, 0 = bf16), parallel ----------
__global__ void detect_k(const unsigned short* x, const unsigned short* w1,
                         const unsigned short* b1, const unsigned short* w2,
                         const unsigned short* b2, int* flags) {
    const int w = threadIdx.x >> 6, l = threadIdx.x & 63;
    if (w >= 5) return;
    const unsigned short* ptrs[5] = {x, w1, b1, w2, b2};
    const unsigned short* p = ptrs[w];
    float mx = 0.f;
    for (int j = l; j < 1024; j += 64) {
        float v = fabsf(bf2f(p[j]));
        if (!(v <= 1e30f)) v = 1e31f;
        if (v > mx) mx = v;
    }
#pragma unroll
    for (int off = 1; off < 64; off <<= 1) mx = fmaxf(mx, __shfl_xor(mx, off, 64));
    if (l == 0) flags[w] = (mx > 1e3f) ? 1 : 0;
}

// ---------- X -> bf16 (convert or copy), 8 elems/thread ----------
__global__ __launch_bounds__(256) void cvt_x(
    const float* __restrict__ Xf, const unsigned short* __restrict__ Xh,
    unsigned short* __restrict__ Xb, const int* __restrict__ flags, int n8) {
    int i = blockIdx.x * 256 + threadIdx.x;
    if (i >= n8) return;
    if (flags[0]) {
        float4 a = ((const float4*)Xf)[(size_t)i * 2];
        float4 b = ((const float4*)Xf)[(size_t)i * 2 + 1];
        *(short8*)&Xb[(size_t)i * 8] = cvt8(a, b);
    } else {
        ((uint4*)Xb)[i] = ((const uint4*)Xh)[i];
    }
}

// ---------- tiled transpose+convert W[R][C] -> bf16 Wt[C][R] (both weights) ----------
__device__ __forceinline__ void wt_body(
    unsigned short (*tile)[65], const float* __restrict__ Wf,
    const unsigned short* __restrict__ Wh, unsigned short* __restrict__ Wt,
    int R, int C, bool f32, int bx, int by, int t) {

    const int c0 = bx * 64, r0 = by * 64;
    const int ri = t >> 2, cj = (t & 3) * 16;

    if (f32) {
#pragma unroll
        for (int u = 0; u < 4; u++) {
            float4 v = *(const float4*)&Wf[(size_t)(r0 + ri) * C + c0 + cj + u * 4];
            tile[ri][cj + u * 4 + 0] = f2bf(v.x);
            tile[ri][cj + u * 4 + 1] = f2bf(v.y);
            tile[ri][cj + u * 4 + 2] = f2bf(v.z);
            tile[ri][cj + u * 4 + 3] = f2bf(v.w);
        }
    } else {
        uint4 a = *(const uint4*)&Wh[(size_t)(r0 + ri) * C + c0 + cj];
        uint4 b = *(const uint4*)&Wh[(size_t)(r0 + ri) * C + c0 + cj + 8];
        *(uint4*)&tile[ri][cj] = a;
        *(uint4*)&tile[ri][cj + 8] = b;
    }
    __syncthreads();

    const int ci = t >> 2, rj = (t & 3) * 16;
    unsigned short tmp[16];
#pragma unroll
    for (int u = 0; u < 16; u++) tmp[u] = tile[rj + u][ci];
    *(uint4*)&Wt[(size_t)(c0 + ci) * R + r0 + rj]     = *(uint4*)&tmp[0];
    *(uint4*)&Wt[(size_t)(c0 + ci) * R + r0 + rj + 8] = *(uint4*)&tmp[8];
}

// grid (36, 24): y<12 -> W1 [768][2304]; y>=12 (x<12) -> W2 [768][768]
__global__ __launch_bounds__(256) void convert_wt_both(
    const float* __restrict__ Wf1, const unsigned short* __restrict__ Wh1,
    unsigned short* __restrict__ Wt1,
    const float* __restrict__ Wf2, const unsigned short* __restrict__ Wh2,
    unsigned short* __restrict__ Wt2, const int* __restrict__ flags) {

    __shared__ unsigned short tile[64][65];
    const int t = threadIdx.x;
    if (blockIdx.y < 12) {
        wt_body(tile, Wf1, Wh1, Wt1, 768, 2304, flags[1] != 0,
                (int)blockIdx.x, (int)blockIdx.y, t);
    } else {
        if (blockIdx.x >= 12) return;
        wt_body(tile, Wf2, Wh2, Wt2, 768, 768, flags[3] != 0,
                (int)blockIdx.x, (int)blockIdx.y - 12, t);
    }
}

// ---------- MFMA GEMM: C[M,N] = A[M,K] @ Bt[N,K]^T + bias ----------
// BK=64 per K-step (two 32-wide halves in LDS [2][128][32]) -> 32 MFMA per
// barrier pair. LDS = 32 KB/block -> 4 blocks/CU; at (256,4) = 16 waves/CU
// the implicit wave-level overlap (m114) covers the barrier drains better
// than explicit 2/3-buffer pipelines (r9/r10 both regressed).
// aFidx<0: A bf16 via global_load_lds. aFidx>=0 + fp32 flag: register-stage+cvt
// (uncoalesced; cold path only -- r7 measured 108us on the hot path).
// mode 0: scatter QKV -> Q[BH,S,hd] (pre-scaled by QSCALE), K[BH,S,hd],
//         Vt[BH,hd,S] (bf16)                                          (N=2304)
// mode 1: store fp32 to outf[M,DMODEL]                                (N=768)
// XCD-aware bijective block swizzle for L2 locality.
__global__ __launch_bounds__(256, 4) void gemm_bt(
    const float* __restrict__ Af, const unsigned short* __restrict__ Ah,
    const unsigned short* __restrict__ Bt,
    const float* __restrict__ biasf, const unsigned short* __restrict__ biash,
    int K, int mode, const int* __restrict__ flags, int aFidx, int bFidx,
    unsigned short* __restrict__ out0, unsigned short* __restrict__ out1,
    unsigned short* __restrict__ out2, float* __restrict__ outf) {

    __shared__ __align__(16) unsigned short As[2][128][32];
    __shared__ __align__(16) unsigned short Bs[2][128][32];

    int bx = blockIdx.x, by = blockIdx.y;
    {
        const int nwg = (int)(gridDim.x * gridDim.y);
        if ((nwg & 7) == 0) {
            int bid = by * gridDim.x + bx;
            const int cpx = nwg >> 3;
            bid = (bid & 7) * cpx + (bid >> 3);
            bx = bid % gridDim.x;
            by = bid / gridDim.x;
        }
    }
    const int mBase = by * 128;
    const int nBase = bx * 128;
    const int t = threadIdx.x;
    const int w = t >> 6, l = t & 63, lr = l & 15, lk = l >> 4;
    const int wr = w >> 1, wc = w & 1;

    const bool af32 = (aFidx >= 0) && (flags[aFidx] != 0);
    const bool bf32 = flags[bFidx] != 0;

    f32x4 zero = {0.f, 0.f, 0.f, 0.f};
    f32x4 acc[4][4];
#pragma unroll
    for (int i = 0; i < 4; i++)
#pragma unroll
        for (int j = 0; j < 4; j++) acc[i][j] = zero;

    const int arow2 = t >> 1;          // af32 path: row 0..127
    const int ha32 = t & 1;            // af32 path: k-half
    const float* Afp = Af + (size_t)mBase * K;
    const unsigned short* Ahp = Ah + (size_t)mBase * K;
    const unsigned short* Bp = Bt + (size_t)nBase * K;

    unsigned short* BsF = &Bs[0][0][0];
    unsigned short* AsF = &As[0][0][0];

    for (int k0 = 0; k0 < K; k0 += 64) {
        // stage B: 1024 granules of 16B; LDS granule c == [ha][row][g2]
#pragma unroll
        for (int q = 0; q < 4; q++) {
            const int c = q * 256 + t;
            const int row = (c >> 2) & 127;
            const int ha = c >> 9;
            const int g2 = c & 3;
            gload16(&Bp[(size_t)row * K + k0 + ha * 32 + g2 * 8],
                    BsF + (size_t)(q * 256 + w * 64) * 8);
        }
        if (af32) {
#pragma unroll
            for (int u = 0; u < 4; u++) {
                float4 f0 = *(const float4*)&Afp[(size_t)arow2 * K + k0 + ha32 * 32 + u * 8];
                float4 f1 = *(const float4*)&Afp[(size_t)arow2 * K + k0 + ha32 * 32 + u * 8 + 4];
                *(short8*)&As[ha32][arow2][u * 8] = cvt8(f0, f1);
            }
        } else {
#pragma unroll
            for (int q = 0; q < 4; q++) {
                const int c = q * 256 + t;
                const int row = (c >> 2) & 127;
                const int ha = c >> 9;
                const int g2 = c & 3;
                gload16(&Ahp[(size_t)row * K + k0 + ha * 32 + g2 * 8],
                        AsF + (size_t)(q * 256 + w * 64) * 8);
            }
        }
        __syncthreads();

#pragma unroll
        for (int ha = 0; ha < 2; ha++) {
            short8 a[4], b[4];
#pragma unroll
            for (int i = 0; i < 4; i++)
                a[i] = *(const short8*)&As[ha][wr * 64 + i * 16 + lr][lk * 8];
#pragma unroll
            for (int j = 0; j < 4; j++)
                b[j] = *(const short8*)&Bs[ha][wc * 64 + j * 16 + lr][lk * 8];
#pragma unroll
            for (int i = 0; i < 4; i++)
#pragma unroll
                for (int j = 0; j < 4; j++) acc[i][j] = mfma16(a[i], b[j], acc[i][j]);
        }
        __syncthreads();
    }

    // epilogue: C/D layout col=lane&15, row=quad*4+r
#pragma unroll
    for (int j = 0; j < 4; j++) {
        int col = nBase + wc * 64 + j * 16 + lr;
        float bv = bf32 ? biasf[col] : bf2f(biash[col]);
        if (mode == 0 && col >= 1536) {
            // Vt[h][d][s]: 4 consecutive s -> one 8B store
            int c2 = col - 1536;
            int h = c2 >> 6, d = c2 & 63;
#pragma unroll
            for (int i = 0; i < 4; i++) {
                int row0 = mBase + wr * 64 + i * 16 + lk * 4;
                int bb = row0 >> 11, s0 = row0 & 2047;
                short4v hv4;
#pragma unroll
                for (int r = 0; r < 4; r++) hv4[r] = (short)f2bf(acc[i][j][r] + bv);
                *(short4v*)&out2[(((size_t)(bb * NHEAD + h)) * HD + d) * SEQ + s0] = hv4;
            }
        } else {
#pragma unroll
            for (int i = 0; i < 4; i++) {
                int row0 = mBase + wr * 64 + i * 16 + lk * 4;
#pragma unroll
                for (int r = 0; r < 4; r++) {
                    int row = row0 + r;
                    float fv = acc[i][j][r] + bv;
                    if (mode == 0) {
                        int bb = row >> 11;
                        int s  = row & 2047;
                        if (col < 768) {
                            // Q: fold softmax scale here (saves VALU in flash)
                            int h = col >> 6, d = col & 63;
                            out0[(((size_t)(bb * NHEAD + h)) * SEQ + s) * HD + d] =
                                f2bf(fv * QSCALE);
                        } else {
                            int c2 = col - 768;
                            int h = c2 >> 6, d = c2 & 63;
                            out1[(((size_t)(bb * NHEAD + h)) * SEQ + s) * HD + d] =
                                f2bf(fv);
                        }
                    } else {
                        outf[(size_t)row * DMODEL + col] = fv;
                    }
                }
            }
        }
    }
}

// ---------- flash attention v7 (r8 best config): counted-vmcnt pipeline ----------
// 3-buffer K/V (48 KB), prefetch 2 tiles ahead, vmcnt(4) across raw s_barrier;
// (256,3) with VGPR 84 -- the register/occupancy equilibrium this kernel is
// balanced on. (256,4) forced VGPR 84->64 and spilled (r12: WRITE 185 MB);
// x3 unrolling tripled live ranges and spilled (r10: WRITE 214 MB). Keep.
#define STAGE(buf, tile) do {                                                  \
    _Pragma("unroll")                                                          \
    for (int q_ = 0; q_ < 2; ++q_) {                                           \
        const int c_ = w * 128 + q_ * 64 + l;                                  \
        const int row_ = c_ >> 3;                                              \
        const int ch_ = (c_ & 7) ^ (row_ & 7);                                 \
        gload16(&Kp[(size_t)((tile) * 64 + row_) * HD + ch_ * 8],              \
                &Ks[buf][(w * 128 + q_ * 64) * 8]);                            \
        gload16(&Vp[(size_t)row_ * SEQ + (tile) * 64 + ch_ * 8],               \
                &Vs[buf][(w * 128 + q_ * 64) * 8]);                            \
    }                                                                          \
} while (0)

__global__ __launch_bounds__(256, 3) void flash_attn(
    const unsigned short* __restrict__ Q, const unsigned short* __restrict__ Km,
    const unsigned short* __restrict__ Vt, unsigned short* __restrict__ Oatt) {

    const int h  = blockIdx.x;
    const int px = (7 * blockIdx.y + blockIdx.x + blockIdx.z) & 15;  // scrambled pair idx
    const int b  = blockIdx.z;
    const int bh = b * NHEAD + h;
    const int qtA = 31 - px;          // heavy q-tile (16..31)
    const int qtB = px;               // light q-tile (0..15)
    const int t = threadIdx.x, w = t >> 6, l = t & 63, lr = l & 15, lk = l >> 4;
    const int qbA = qtA * 64 + w * 16;
    const int qbB = qtB * 64 + w * 16;

    const unsigned short* Qp = Q + (size_t)bh * SEQ * HD;
    const unsigned short* Kp = Km + (size_t)bh * SEQ * HD;
    const unsigned short* Vp = Vt + (size_t)bh * HD * SEQ;

    __shared__ __align__(16) unsigned short Ks[3][4096];
    __shared__ __align__(16) unsigned short Vs[3][4096];

    short8 qA0 = *(const short8*)&Qp[(size_t)(qbA + lr) * HD + lk * 8];
    short8 qA1 = *(const short8*)&Qp[(size_t)(qbA + lr) * HD + 32 + lk * 8];
    short8 qB0 = *(const short8*)&Qp[(size_t)(qbB + lr) * HD + lk * 8];
    short8 qB1 = *(const short8*)&Qp[(size_t)(qbB + lr) * HD + 32 + lk * 8];

    f32x4 zero = {0.f, 0.f, 0.f, 0.f};
    f32x4 oA[4], oB[4];
    float lsumA = 0.f, lsumB = 0.f;
#pragma unroll
    for (int dt = 0; dt < 4; dt++) { oA[dt] = zero; oB[dt] = zero; }

    // prologue: stage tiles 0 and 1 (qtA >= 16 always, tile 1 exists)
    STAGE(0, 0);
    STAGE(1, 1);
    asm volatile("s_waitcnt vmcnt(4)" ::: "memory");   // tile 0 landed
    __builtin_amdgcn_s_barrier();

    int cur = 0;
    for (int kt = 0; kt <= qtA; ++kt) {
        const bool pf = (kt + 2 <= qtA);
        if (pf) {
            const int st = (cur == 0) ? 2 : cur - 1;   // (cur+2) mod 3
            STAGE(st, kt + 2);
        }
        const bool doB = (kt <= qtB);

        // ---- QK^T (swapped: K as A, Q as B), K fragments read once ----
        f32x4 s0[4], s1[4];
        __builtin_amdgcn_s_setprio(1);
#pragma unroll
        for (int ct = 0; ct < 4; ct++) {
            const int row = ct * 16 + lr, sw = row & 7;
            short8 k0 = *(const short8*)&Ks[cur][(row * 8 + (lk ^ sw)) * 8];
            short8 k1 = *(const short8*)&Ks[cur][(row * 8 + ((4 | lk) ^ sw)) * 8];
            s0[ct] = mfma16(k0, qA0, zero);
            s0[ct] = mfma16(k1, qA1, s0[ct]);
            if (doB) {
                s1[ct] = mfma16(k0, qB0, zero);
                s1[ct] = mfma16(k1, qB1, s1[ct]);
            }
        }
        __builtin_amdgcn_s_setprio(0);

        // ---- V fragments for 16x16x16 PV: B[n=d=lr][k=key=ct*16+lk*4+j] ----
        short4v vf[4][4];
#pragma unroll
        for (int dt = 0; dt < 4; dt++) {
            const int row = dt * 16 + lr;          // d index
            const int sw = row & 7;
#pragma unroll
            for (int ct = 0; ct < 4; ct++) {
                const int g = 2 * ct + (lk >> 1);  // 16B source granule
                const int hh = lk & 1;             // 8B half within granule
                vf[dt][ct] = *(const short4v*)&Vs[cur][(row * 8 + (g ^ sw)) * 8 + hh * 4];
            }
        }

        // ---- strip A: softmax in-register (Q pre-scaled -> just exp2), pack, PV ----
        short4v paA[4];
        {
            float p[4][4];
#pragma unroll
            for (int ct = 0; ct < 4; ct++)
#pragma unroll
                for (int r = 0; r < 4; r++) p[ct][r] = exp2f(s0[ct][r]);
            if (kt == qtA) {   // causal mask: zero after exp2
                const int qrow = qbA + lr;
#pragma unroll
                for (int ct = 0; ct < 4; ct++)
#pragma unroll
                    for (int r = 0; r < 4; r++) {
                        const int key = kt * 64 + ct * 16 + lk * 4 + r;
                        if (key > qrow) p[ct][r] = 0.0f;
                    }
            }
#pragma unroll
            for (int ct = 0; ct < 4; ct++)
                lsumA += (p[ct][0] + p[ct][1]) + (p[ct][2] + p[ct][3]);
#pragma unroll
            for (int ct = 0; ct < 4; ct++) {
                short4v pk;
#pragma unroll
                for (int r = 0; r < 4; r++) pk[r] = (short)f2bfn(p[ct][r]);
                paA[ct] = pk;
            }
        }
        __builtin_amdgcn_s_setprio(1);
#pragma unroll
        for (int dt = 0; dt < 4; dt++)
#pragma unroll
            for (int ct = 0; ct < 4; ct++)
                oA[dt] = mfma16k16(paA[ct], vf[dt][ct], oA[dt]);
        __builtin_amdgcn_s_setprio(0);

        // ---- strip B ----
        if (doB) {
            short4v paB[4];
            float p[4][4];
#pragma unroll
            for (int ct = 0; ct < 4; ct++)
#pragma unroll
                for (int r = 0; r < 4; r++) p[ct][r] = exp2f(s1[ct][r]);
            if (kt == qtB) {
                const int qrow = qbB + lr;
#pragma unroll
                for (int ct = 0; ct < 4; ct++)
#pragma unroll
                    for (int r = 0; r < 4; r++) {
                        const int key = kt * 64 + ct * 16 + lk * 4 + r;
                        if (key > qrow) p[ct][r] = 0.0f;
                    }
            }
#pragma unroll
            for (int ct = 0; ct < 4; ct++)
                lsumB += (p[ct][0] + p[ct][1]) + (p[ct][2] + p[ct][3]);
#pragma unroll
            for (int ct = 0; ct < 4; ct++) {
                short4v pk;
#pragma unroll
                for (int r = 0; r < 4; r++) pk[r] = (short)f2bfn(p[ct][r]);
                paB[ct] = pk;
            }
            __builtin_amdgcn_s_setprio(1);
#pragma unroll
            for (int dt = 0; dt < 4; dt++)
#pragma unroll
                for (int ct = 0; ct < 4; ct++)
                    oB[dt] = mfma16k16(paB[ct], vf[dt][ct], oB[dt]);
            __builtin_amdgcn_s_setprio(0);
        }

        // ---- counted-vmcnt barrier: tile kt+1 landed, kt+2 stays in flight ----
        if (kt < qtA) {
            if (pf) asm volatile("s_waitcnt vmcnt(4)" ::: "memory");
            else    asm volatile("s_waitcnt vmcnt(0)" ::: "memory");
            __builtin_amdgcn_s_barrier();
        }
        cur = (cur == 2) ? 0 : cur + 1;
    }

    // row-sum lives per lane at q=lr; reduce across the 4 lk groups
    lsumA += __shfl_xor(lsumA, 16, 64);
    lsumA += __shfl_xor(lsumA, 32, 64);
    lsumB += __shfl_xor(lsumB, 16, 64);
    lsumB += __shfl_xor(lsumB, 32, 64);

#pragma unroll
    for (int r = 0; r < 4; r++) {
        const float invA = 1.0f / __shfl(lsumA, lk * 4 + r, 64);
        const float invB = 1.0f / __shfl(lsumB, lk * 4 + r, 64);
        const int rowA = qbA + lk * 4 + r;
        const int rowB = qbB + lk * 4 + r;
#pragma unroll
        for (int dt = 0; dt < 4; dt++) {
            Oatt[((size_t)(b * SEQ) + rowA) * DMODEL + h * HD + dt * 16 + lr] =
                f2bfn(oA[dt][r] * invA);
            Oatt[((size_t)(b * SEQ) + rowB) * DMODEL + h * HD + dt * 16 + lr] =
                f2bfn(oB[dt][r] * invB);
        }
    }
}

extern "C" void kernel_launch(void* const* d_in, const int* in_sizes, int n_in,
                              void* d_out, int out_size, void* d_ws, size_t ws_size,
                              hipStream_t stream) {
    const void *X = d_in[0], *W1 = d_in[1], *b1 = d_in[2], *W2 = d_in[3], *b2 = d_in[4];
    for (int i = 0; i < n_in; i++) {
        switch (in_sizes[i]) {
            case NBATCH * SEQ * DMODEL: X  = d_in[i]; break;
            case DMODEL * 3 * DMODEL:   W1 = d_in[i]; break;
            case 3 * DMODEL:            b1 = d_in[i]; break;
            case DMODEL * DMODEL:       W2 = d_in[i]; break;
            case DMODEL:                b2 = d_in[i]; break;
        }
    }
    float* out = (float*)d_out;

    int* flags = (int*)d_ws;
    unsigned short* base = (unsigned short*)d_ws + 64;
    unsigned short* Wt1 = base;                                 // [2304][768]
    unsigned short* Wt2 = Wt1 + (size_t)2304 * 768;             // [768][768]

    const size_t headElems = (size_t)NHEAD * SEQ * HD;          // 1.57M / batch
    const size_t xElems = (size_t)NBATCH * SEQ * DMODEL;        // 6.29M
    const size_t fixedElems = 64 + (size_t)2304 * 768 + (size_t)768 * 768;
    const size_t mergedNeed = (fixedElems + xElems + 4 * NBATCH * headElems) * 2 + 1024;
    const bool merged = ws_size >= mergedNeed;

    detect_k<<<1, 320, 0, stream>>>(
        (const unsigned short*)X, (const unsigned short*)W1,
        (const unsigned short*)b1, (const unsigned short*)W2,
        (const unsigned short*)b2, flags);

    convert_wt_both<<<dim3(36, 24), 256, 0, stream>>>(
        (const float*)W1, (const unsigned short*)W1, Wt1,
        (const float*)W2, (const unsigned short*)W2, Wt2, flags);

    if (merged) {
        unsigned short* Xb  = Wt2 + (size_t)768 * 768;          // [8192][768] bf16
        unsigned short* Qw  = Xb + xElems;
        unsigned short* Kw  = Qw + (size_t)NBATCH * headElems;
        unsigned short* Vtw = Kw + (size_t)NBATCH * headElems;
        unsigned short* Aw  = Vtw + (size_t)NBATCH * headElems;

        // coalesced X -> bf16 pass (in-gemm fp32 A path measured 108us in r7:
        // uncoalesced loads + LDS write conflicts; separate pass is better)
        cvt_x<<<(int)((xElems / 8 + 255) / 256), 256, 0, stream>>>(
            (const float*)X, (const unsigned short*)X, Xb, flags, (int)(xElems / 8));

        gemm_bt<<<dim3(2304 / 128, NBATCH * SEQ / 128), 256, 0, stream>>>(
            nullptr, Xb, Wt1,
            (const float*)b1, (const unsigned short*)b1,
            DMODEL, 0, flags, -1, 2, Qw, Kw, Vtw, nullptr);

        flash_attn<<<dim3(NHEAD, 16, NBATCH), 256, 0, stream>>>(Qw, Kw, Vtw, Aw);

        gemm_bt<<<dim3(768 / 128, NBATCH * SEQ / 128), 256, 0, stream>>>(
            nullptr, Aw, Wt2,
            (const float*)b2, (const unsigned short*)b2,
            DMODEL, 1, flags, -1, 4, nullptr, nullptr, nullptr, out);
    } else {
        unsigned short* Qw  = Wt2 + (size_t)768 * 768;
        unsigned short* Kw  = Qw + headElems;
        unsigned short* Vtw = Kw + headElems;
        unsigned short* Aw  = Vtw + headElems;
        for (int batch = 0; batch < NBATCH; ++batch) {
            const size_t xoff = (size_t)batch * SEQ * DMODEL;

            gemm_bt<<<dim3(2304 / 128, SEQ / 128), 256, 0, stream>>>(
                (const float*)X + xoff, (const unsigned short*)X + xoff, Wt1,
                (const float*)b1, (const unsigned short*)b1,
                DMODEL, 0, flags, 0, 2, Qw, Kw, Vtw, nullptr);

            flash_attn<<<dim3(NHEAD, 16, 1), 256, 0, stream>>>(Qw, Kw, Vtw, Aw);

            gemm_bt<<<dim3(768 / 128, SEQ / 128), 256, 0, stream>>>(
                nullptr, Aw, Wt2,
                (const float*)b2, (const unsigned short*)b2,
                DMODEL, 1, flags, -1, 4, nullptr, nullptr, nullptr, out + xoff);
        }
    }
}

// Round 15
// 209.699 us; speedup vs baseline: 1.7304x; 1.0713x over previous
//
#include <hip/hip_runtime.h>
#include <stdint.h>

// ---------- types ----------
typedef __attribute__((ext_vector_type(8))) short short8;
typedef __attribute__((ext_vector_type(4))) short short4v;
typedef __attribute__((ext_vector_type(8))) __bf16 bf16x8;
typedef __attribute__((ext_vector_type(4))) float f32x4;

#define SEQ 2048
#define DMODEL 768
#define NHEAD 12
#define HD 64
#define NBATCH 4

// softmax scale folded into Q at QKV-projection epilogue: 1/sqrt(64) * log2(e)
#define QSCALE 0.18033688011112042f

__device__ __forceinline__ float bf2f(unsigned short u) {
    return __uint_as_float(((unsigned int)u) << 16);
}
__device__ __forceinline__ unsigned short f2bf(float f) {
    unsigned int u = __float_as_uint(f);
    u += 0x7fffu + ((u >> 16) & 1u);   // round-to-nearest-even
    return (unsigned short)(u >> 16);
}
// native f32 -> bf16 (RNE), lets the compiler emit v_cvt_pk_bf16_f32
__device__ __forceinline__ unsigned short f2bfn(float f) {
    union { __bf16 h; unsigned short u; } cv;
    cv.h = (__bf16)f;
    return cv.u;
}
// raw v_exp_f32: D = 2^S0 over the full range (no libm denorm/clamp fixups)
__device__ __forceinline__ float exp2raw(float x) {
#if __has_builtin(__builtin_amdgcn_exp2f)
    return __builtin_amdgcn_exp2f(x);
#else
    float r;
    asm("v_exp_f32 %0, %1" : "=v"(r) : "v"(x));
    return r;
#endif
}
__device__ __forceinline__ short8 cvt8(float4 a, float4 b) {
    short8 r;
    r[0] = (short)f2bf(a.x); r[1] = (short)f2bf(a.y);
    r[2] = (short)f2bf(a.z); r[3] = (short)f2bf(a.w);
    r[4] = (short)f2bf(b.x); r[5] = (short)f2bf(b.y);
    r[6] = (short)f2bf(b.z); r[7] = (short)f2bf(b.w);
    return r;
}
__device__ __forceinline__ f32x4 mfma16(short8 a, short8 b, f32x4 c) {
    return __builtin_amdgcn_mfma_f32_16x16x32_bf16(
        __builtin_bit_cast(bf16x8, a), __builtin_bit_cast(bf16x8, b), c, 0, 0, 0);
}
// 16x16x16 bf16 MFMA: A/B = 4 bf16 (2 VGPR). Lane layout:
//   A[m=lane&15][k=(lane>>4)*4+j], B[n=lane&15][k=(lane>>4)*4+j],
//   D[m=(lane>>4)*4+r][n=lane&15]
__device__ __forceinline__ f32x4 mfma16k16(short4v a, short4v b, f32x4 c) {
#if __has_builtin(__builtin_amdgcn_mfma_f32_16x16x16bf16_1k)
    return __builtin_amdgcn_mfma_f32_16x16x16bf16_1k(a, b, c, 0, 0, 0);
#else
    asm("v_mfma_f32_16x16x16_bf16 %0, %1, %2, %0" : "+v"(c) : "v"(a), "v"(b));
    return c;
#endif
}
// async global->LDS, 16B per lane; dst = wave-uniform base + lane*16
__device__ __forceinline__ void gload16(const unsigned short* g, unsigned short* l) {
    __builtin_amdgcn_global_load_lds(
        (const __attribute__((address_space(1))) unsigned int*)g,
        (__attribute__((address_space(3))) unsigned int*)l, 16, 0, 0);
}

// ---------- runtime dtype detection (1 = fp32, 0 = bf16), parallel ----------
__global__ void detect_k(const unsigned short* x, const unsigned short* w1,
                         const unsigned short* b1, const unsigned short* w2,
                         const unsigned short* b2, int* flags) {
    const int w = threadIdx.x >> 6, l = threadIdx.x & 63;
    if (w >= 5) return;
    const unsigned short* ptrs[5] = {x, w1, b1, w2, b2};
    const unsigned short* p = ptrs[w];
    float mx = 0.f;
    for (int j = l; j < 1024; j += 64) {
        float v = fabsf(bf2f(p[j]));
        if (!(v <= 1e30f)) v = 1e31f;
        if (v > mx) mx = v;
    }
#pragma unroll
    for (int off = 1; off < 64; off <<= 1) mx = fmaxf(mx, __shfl_xor(mx, off, 64));
    if (l == 0) flags[w] = (mx > 1e3f) ? 1 : 0;
}

// ---------- tiled transpose+convert W[R][C] -> bf16 Wt[C][R] ----------
__device__ __forceinline__ void wt_body(
    unsigned short (*tile)[65], const float* __restrict__ Wf,
    const unsigned short* __restrict__ Wh, unsigned short* __restrict__ Wt,
    int R, int C, bool f32, int bx, int by, int t) {

    const int c0 = bx * 64, r0 = by * 64;
    const int ri = t >> 2, cj = (t & 3) * 16;

    if (f32) {
#pragma unroll
        for (int u = 0; u < 4; u++) {
            float4 v = *(const float4*)&Wf[(size_t)(r0 + ri) * C + c0 + cj + u * 4];
            tile[ri][cj + u * 4 + 0] = f2bf(v.x);
            tile[ri][cj + u * 4 + 1] = f2bf(v.y);
            tile[ri][cj + u * 4 + 2] = f2bf(v.z);
            tile[ri][cj + u * 4 + 3] = f2bf(v.w);
        }
    } else {
        uint4 a = *(const uint4*)&Wh[(size_t)(r0 + ri) * C + c0 + cj];
        uint4 b = *(const uint4*)&Wh[(size_t)(r0 + ri) * C + c0 + cj + 8];
        *(uint4*)&tile[ri][cj] = a;
        *(uint4*)&tile[ri][cj + 8] = b;
    }
    __syncthreads();

    const int ci = t >> 2, rj = (t & 3) * 16;
    unsigned short tmp[16];
#pragma unroll
    for (int u = 0; u < 16; u++) tmp[u] = tile[rj + u][ci];
    *(uint4*)&Wt[(size_t)(c0 + ci) * R + r0 + rj]     = *(uint4*)&tmp[0];
    *(uint4*)&Wt[(size_t)(c0 + ci) * R + r0 + rj + 8] = *(uint4*)&tmp[8];
}

// ---------- merged preprocessing: X->bf16 convert + both weight transposes ----------
// 1-D grid: bid < cvtBlocks           -> cvt_x body (i = bid*256 + t)
//           next 432 blocks (36 x 12) -> W1 [768][2304] transpose
//           next 144 blocks (12 x 12) -> W2 [768][768]  transpose
// cvtBlocks==0 in the non-merged fallback (no Xb buffer).
__global__ __launch_bounds__(256) void prep(
    const float* __restrict__ Xf, const unsigned short* __restrict__ Xh,
    unsigned short* __restrict__ Xb, int n8, int cvtBlocks,
    const float* __restrict__ Wf1, const unsigned short* __restrict__ Wh1,
    unsigned short* __restrict__ Wt1,
    const float* __restrict__ Wf2, const unsigned short* __restrict__ Wh2,
    unsigned short* __restrict__ Wt2, const int* __restrict__ flags) {

    const int bid = (int)blockIdx.x;
    const int t = threadIdx.x;

    if (bid < cvtBlocks) {
        int i = bid * 256 + t;
        if (i >= n8) return;
        if (flags[0]) {
            float4 a = ((const float4*)Xf)[(size_t)i * 2];
            float4 b = ((const float4*)Xf)[(size_t)i * 2 + 1];
            *(short8*)&Xb[(size_t)i * 8] = cvt8(a, b);
        } else {
            ((uint4*)Xb)[i] = ((const uint4*)Xh)[i];
        }
        return;
    }

    __shared__ unsigned short tile[64][65];
    const int idx = bid - cvtBlocks;
    if (idx < 432) {
        wt_body(tile, Wf1, Wh1, Wt1, 768, 2304, flags[1] != 0,
                idx % 36, idx / 36, t);
    } else {
        const int i2 = idx - 432;
        wt_body(tile, Wf2, Wh2, Wt2, 768, 768, flags[3] != 0,
                i2 % 12, i2 / 12, t);
    }
}

// ---------- MFMA GEMM: C[M,N] = A[M,K] @ Bt[N,K]^T + bias ----------
// BK=64 per K-step (two 32-wide halves in LDS [2][128][32]) -> 32 MFMA per
// barrier pair. LDS = 32 KB/block -> 4 blocks/CU; at (256,4) = 16 waves/CU
// the implicit wave-level overlap (m114) covers the barrier drains better
// than explicit 2/3-buffer pipelines (r9/r10 both regressed).
// aFidx<0: A bf16 via global_load_lds. aFidx>=0 + fp32 flag: register-stage+cvt
// (uncoalesced; cold path only -- r7 measured 108us on the hot path).
// mode 0: scatter QKV -> Q[BH,S,hd] (pre-scaled by QSCALE), K[BH,S,hd],
//         Vt[BH,hd,S] (bf16)                                          (N=2304)
// mode 1: store fp32 to outf[M,DMODEL]                                (N=768)
// XCD-aware bijective block swizzle for L2 locality.
__global__ __launch_bounds__(256, 4) void gemm_bt(
    const float* __restrict__ Af, const unsigned short* __restrict__ Ah,
    const unsigned short* __restrict__ Bt,
    const float* __restrict__ biasf, const unsigned short* __restrict__ biash,
    int K, int mode, const int* __restrict__ flags, int aFidx, int bFidx,
    unsigned short* __restrict__ out0, unsigned short* __restrict__ out1,
    unsigned short* __restrict__ out2, float* __restrict__ outf) {

    __shared__ __align__(16) unsigned short As[2][128][32];
    __shared__ __align__(16) unsigned short Bs[2][128][32];

    int bx = blockIdx.x, by = blockIdx.y;
    {
        const int nwg = (int)(gridDim.x * gridDim.y);
        if ((nwg & 7) == 0) {
            int bid = by * gridDim.x + bx;
            const int cpx = nwg >> 3;
            bid = (bid & 7) * cpx + (bid >> 3);
            bx = bid % gridDim.x;
            by = bid / gridDim.x;
        }
    }
    const int mBase = by * 128;
    const int nBase = bx * 128;
    const int t = threadIdx.x;
    const int w = t >> 6, l = t & 63, lr = l & 15, lk = l >> 4;
    const int wr = w >> 1, wc = w & 1;

    const bool af32 = (aFidx >= 0) && (flags[aFidx] != 0);
    const bool bf32 = flags[bFidx] != 0;

    f32x4 zero = {0.f, 0.f, 0.f, 0.f};
    f32x4 acc[4][4];
#pragma unroll
    for (int i = 0; i < 4; i++)
#pragma unroll
        for (int j = 0; j < 4; j++) acc[i][j] = zero;

    const int arow2 = t >> 1;          // af32 path: row 0..127
    const int ha32 = t & 1;            // af32 path: k-half
    const float* Afp = Af + (size_t)mBase * K;
    const unsigned short* Ahp = Ah + (size_t)mBase * K;
    const unsigned short* Bp = Bt + (size_t)nBase * K;

    unsigned short* BsF = &Bs[0][0][0];
    unsigned short* AsF = &As[0][0][0];

    for (int k0 = 0; k0 < K; k0 += 64) {
        // stage B: 1024 granules of 16B; LDS granule c == [ha][row][g2]
#pragma unroll
        for (int q = 0; q < 4; q++) {
            const int c = q * 256 + t;
            const int row = (c >> 2) & 127;
            const int ha = c >> 9;
            const int g2 = c & 3;
            gload16(&Bp[(size_t)row * K + k0 + ha * 32 + g2 * 8],
                    BsF + (size_t)(q * 256 + w * 64) * 8);
        }
        if (af32) {
#pragma unroll
            for (int u = 0; u < 4; u++) {
                float4 f0 = *(const float4*)&Afp[(size_t)arow2 * K + k0 + ha32 * 32 + u * 8];
                float4 f1 = *(const float4*)&Afp[(size_t)arow2 * K + k0 + ha32 * 32 + u * 8 + 4];
                *(short8*)&As[ha32][arow2][u * 8] = cvt8(f0, f1);
            }
        } else {
#pragma unroll
            for (int q = 0; q < 4; q++) {
                const int c = q * 256 + t;
                const int row = (c >> 2) & 127;
                const int ha = c >> 9;
                const int g2 = c & 3;
                gload16(&Ahp[(size_t)row * K + k0 + ha * 32 + g2 * 8],
                        AsF + (size_t)(q * 256 + w * 64) * 8);
            }
        }
        __syncthreads();

#pragma unroll
        for (int ha = 0; ha < 2; ha++) {
            short8 a[4], b[4];
#pragma unroll
            for (int i = 0; i < 4; i++)
                a[i] = *(const short8*)&As[ha][wr * 64 + i * 16 + lr][lk * 8];
#pragma unroll
            for (int j = 0; j < 4; j++)
                b[j] = *(const short8*)&Bs[ha][wc * 64 + j * 16 + lr][lk * 8];
#pragma unroll
            for (int i = 0; i < 4; i++)
#pragma unroll
                for (int j = 0; j < 4; j++) acc[i][j] = mfma16(a[i], b[j], acc[i][j]);
        }
        __syncthreads();
    }

    // epilogue: C/D layout col=lane&15, row=quad*4+r
#pragma unroll
    for (int j = 0; j < 4; j++) {
        int col = nBase + wc * 64 + j * 16 + lr;
        float bv = bf32 ? biasf[col] : bf2f(biash[col]);
        if (mode == 0 && col >= 1536) {
            // Vt[h][d][s]: 4 consecutive s -> one 8B store
            int c2 = col - 1536;
            int h = c2 >> 6, d = c2 & 63;
#pragma unroll
            for (int i = 0; i < 4; i++) {
                int row0 = mBase + wr * 64 + i * 16 + lk * 4;
                int bb = row0 >> 11, s0 = row0 & 2047;
                short4v hv4;
#pragma unroll
                for (int r = 0; r < 4; r++) hv4[r] = (short)f2bf(acc[i][j][r] + bv);
                *(short4v*)&out2[(((size_t)(bb * NHEAD + h)) * HD + d) * SEQ + s0] = hv4;
            }
        } else {
#pragma unroll
            for (int i = 0; i < 4; i++) {
                int row0 = mBase + wr * 64 + i * 16 + lk * 4;
#pragma unroll
                for (int r = 0; r < 4; r++) {
                    int row = row0 + r;
                    float fv = acc[i][j][r] + bv;
                    if (mode == 0) {
                        int bb = row >> 11;
                        int s  = row & 2047;
                        if (col < 768) {
                            // Q: fold softmax scale here (saves VALU in flash)
                            int h = col >> 6, d = col & 63;
                            out0[(((size_t)(bb * NHEAD + h)) * SEQ + s) * HD + d] =
                                f2bf(fv * QSCALE);
                        } else {
                            int c2 = col - 768;
                            int h = c2 >> 6, d = c2 & 63;
                            out1[(((size_t)(bb * NHEAD + h)) * SEQ + s) * HD + d] =
                                f2bf(fv);
                        }
                    } else {
                        outf[(size_t)row * DMODEL + col] = fv;
                    }
                }
            }
        }
    }
}

// ---------- flash attention v7 (r8 best config): counted-vmcnt pipeline ----------
// 3-buffer K/V (48 KB), prefetch 2 tiles ahead, vmcnt(4) across raw s_barrier;
// (256,3) with VGPR 84 -- the register/occupancy equilibrium this kernel is
// balanced on. (256,4) forced VGPR 84->64 and spilled (r12: WRITE 185 MB);
// x3 unrolling tripled live ranges and spilled (r10: WRITE 214 MB). Keep.
// exp2 via raw v_exp_f32 (full-range HW op; avoids any libm fixup overhead).
#define STAGE(buf, tile) do {                                                  \
    _Pragma("unroll")                                                          \
    for (int q_ = 0; q_ < 2; ++q_) {                                           \
        const int c_ = w * 128 + q_ * 64 + l;                                  \
        const int row_ = c_ >> 3;                                              \
        const int ch_ = (c_ & 7) ^ (row_ & 7);                                 \
        gload16(&Kp[(size_t)((tile) * 64 + row_) * HD + ch_ * 8],              \
                &Ks[buf][(w * 128 + q_ * 64) * 8]);                            \
        gload16(&Vp[(size_t)row_ * SEQ + (tile) * 64 + ch_ * 8],               \
                &Vs[buf][(w * 128 + q_ * 64) * 8]);                            \
    }                                                                          \
} while (0)

__global__ __launch_bounds__(256, 3) void flash_attn(
    const unsigned short* __restrict__ Q, const unsigned short* __restrict__ Km,
    const unsigned short* __restrict__ Vt, unsigned short* __restrict__ Oatt) {

    const int h  = blockIdx.x;
    const int px = (7 * blockIdx.y + blockIdx.x + blockIdx.z) & 15;  // scrambled pair idx
    const int b  = blockIdx.z;
    const int bh = b * NHEAD + h;
    const int qtA = 31 - px;          // heavy q-tile (16..31)
    const int qtB = px;               // light q-tile (0..15)
    const int t = threadIdx.x, w = t >> 6, l = t & 63, lr = l & 15, lk = l >> 4;
    const int qbA = qtA * 64 + w * 16;
    const int qbB = qtB * 64 + w * 16;

    const unsigned short* Qp = Q + (size_t)bh * SEQ * HD;
    const unsigned short* Kp = Km + (size_t)bh * SEQ * HD;
    const unsigned short* Vp = Vt + (size_t)bh * HD * SEQ;

    __shared__ __align__(16) unsigned short Ks[3][4096];
    __shared__ __align__(16) unsigned short Vs[3][4096];

    short8 qA0 = *(const short8*)&Qp[(size_t)(qbA + lr) * HD + lk * 8];
    short8 qA1 = *(const short8*)&Qp[(size_t)(qbA + lr) * HD + 32 + lk * 8];
    short8 qB0 = *(const short8*)&Qp[(size_t)(qbB + lr) * HD + lk * 8];
    short8 qB1 = *(const short8*)&Qp[(size_t)(qbB + lr) * HD + 32 + lk * 8];

    f32x4 zero = {0.f, 0.f, 0.f, 0.f};
    f32x4 oA[4], oB[4];
    float lsumA = 0.f, lsumB = 0.f;
#pragma unroll
    for (int dt = 0; dt < 4; dt++) { oA[dt] = zero; oB[dt] = zero; }

    // prologue: stage tiles 0 and 1 (qtA >= 16 always, tile 1 exists)
    STAGE(0, 0);
    STAGE(1, 1);
    asm volatile("s_waitcnt vmcnt(4)" ::: "memory");   // tile 0 landed
    __builtin_amdgcn_s_barrier();

    int cur = 0;
    for (int kt = 0; kt <= qtA; ++kt) {
        const bool pf = (kt + 2 <= qtA);
        if (pf) {
            const int st = (cur == 0) ? 2 : cur - 1;   // (cur+2) mod 3
            STAGE(st, kt + 2);
        }
        const bool doB = (kt <= qtB);

        // ---- QK^T (swapped: K as A, Q as B), K fragments read once ----
        f32x4 s0[4], s1[4];
        __builtin_amdgcn_s_setprio(1);
#pragma unroll
        for (int ct = 0; ct < 4; ct++) {
            const int row = ct * 16 + lr, sw = row & 7;
            short8 k0 = *(const short8*)&Ks[cur][(row * 8 + (lk ^ sw)) * 8];
            short8 k1 = *(const short8*)&Ks[cur][(row * 8 + ((4 | lk) ^ sw)) * 8];
            s0[ct] = mfma16(k0, qA0, zero);
            s0[ct] = mfma16(k1, qA1, s0[ct]);
            if (doB) {
                s1[ct] = mfma16(k0, qB0, zero);
                s1[ct] = mfma16(k1, qB1, s1[ct]);
            }
        }
        __builtin_amdgcn_s_setprio(0);

        // ---- V fragments for 16x16x16 PV: B[n=d=lr][k=key=ct*16+lk*4+j] ----
        short4v vf[4][4];
#pragma unroll
        for (int dt = 0; dt < 4; dt++) {
            const int row = dt * 16 + lr;          // d index
            const int sw = row & 7;
#pragma unroll
            for (int ct = 0; ct < 4; ct++) {
                const int g = 2 * ct + (lk >> 1);  // 16B source granule
                const int hh = lk & 1;             // 8B half within granule
                vf[dt][ct] = *(const short4v*)&Vs[cur][(row * 8 + (g ^ sw)) * 8 + hh * 4];
            }
        }

        // ---- strip A: softmax in-register (Q pre-scaled -> just exp2), pack, PV ----
        short4v paA[4];
        {
            float p[4][4];
#pragma unroll
            for (int ct = 0; ct < 4; ct++)
#pragma unroll
                for (int r = 0; r < 4; r++) p[ct][r] = exp2raw(s0[ct][r]);
            if (kt == qtA) {   // causal mask: zero after exp2
                const int qrow = qbA + lr;
#pragma unroll
                for (int ct = 0; ct < 4; ct++)
#pragma unroll
                    for (int r = 0; r < 4; r++) {
                        const int key = kt * 64 + ct * 16 + lk * 4 + r;
                        if (key > qrow) p[ct][r] = 0.0f;
                    }
            }
#pragma unroll
            for (int ct = 0; ct < 4; ct++)
                lsumA += (p[ct][0] + p[ct][1]) + (p[ct][2] + p[ct][3]);
#pragma unroll
            for (int ct = 0; ct < 4; ct++) {
                short4v pk;
#pragma unroll
                for (int r = 0; r < 4; r++) pk[r] = (short)f2bfn(p[ct][r]);
                paA[ct] = pk;
            }
        }
        __builtin_amdgcn_s_setprio(1);
#pragma unroll
        for (int dt = 0; dt < 4; dt++)
#pragma unroll
            for (int ct = 0; ct < 4; ct++)
                oA[dt] = mfma16k16(paA[ct], vf[dt][ct], oA[dt]);
        __builtin_amdgcn_s_setprio(0);

        // ---- strip B ----
        if (doB) {
            short4v paB[4];
            float p[4][4];
#pragma unroll
            for (int ct = 0; ct < 4; ct++)
#pragma unroll
                for (int r = 0; r < 4; r++) p[ct][r] = exp2raw(s1[ct][r]);
            if (kt == qtB) {
                const int qrow = qbB + lr;
#pragma unroll
                for (int ct = 0; ct < 4; ct++)
#pragma unroll
                    for (int r = 0; r < 4; r++) {
                        const int key = kt * 64 + ct * 16 + lk * 4 + r;
                        if (key > qrow) p[ct][r] = 0.0f;
                    }
            }
#pragma unroll
            for (int ct = 0; ct < 4; ct++)
                lsumB += (p[ct][0] + p[ct][1]) + (p[ct][2] + p[ct][3]);
#pragma unroll
            for (int ct = 0; ct < 4; ct++) {
                short4v pk;
#pragma unroll
                for (int r = 0; r < 4; r++) pk[r] = (short)f2bfn(p[ct][r]);
                paB[ct] = pk;
            }
            __builtin_amdgcn_s_setprio(1);
#pragma unroll
            for (int dt = 0; dt < 4; dt++)
#pragma unroll
                for (int ct = 0; ct < 4; ct++)
                    oB[dt] = mfma16k16(paB[ct], vf[dt][ct], oB[dt]);
            __builtin_amdgcn_s_setprio(0);
        }

        // ---- counted-vmcnt barrier: tile kt+1 landed, kt+2 stays in flight ----
        if (kt < qtA) {
            if (pf) asm volatile("s_waitcnt vmcnt(4)" ::: "memory");
            else    asm volatile("s_waitcnt vmcnt(0)" ::: "memory");
            __builtin_amdgcn_s_barrier();
        }
        cur = (cur == 2) ? 0 : cur + 1;
    }

    // row-sum lives per lane at q=lr; reduce across the 4 lk groups
    lsumA += __shfl_xor(lsumA, 16, 64);
    lsumA += __shfl_xor(lsumA, 32, 64);
    lsumB += __shfl_xor(lsumB, 16, 64);
    lsumB += __shfl_xor(lsumB, 32, 64);

#pragma unroll
    for (int r = 0; r < 4; r++) {
        const float invA = 1.0f / __shfl(lsumA, lk * 4 + r, 64);
        const float invB = 1.0f / __shfl(lsumB, lk * 4 + r, 64);
        const int rowA = qbA + lk * 4 + r;
        const int rowB = qbB + lk * 4 + r;
#pragma unroll
        for (int dt = 0; dt < 4; dt++) {
            Oatt[((size_t)(b * SEQ) + rowA) * DMODEL + h * HD + dt * 16 + lr] =
                f2bfn(oA[dt][r] * invA);
            Oatt[((size_t)(b * SEQ) + rowB) * DMODEL + h * HD + dt * 16 + lr] =
                f2bfn(oB[dt][r] * invB);
        }
    }
}

extern "C" void kernel_launch(void* const* d_in, const int* in_sizes, int n_in,
                              void* d_out, int out_size, void* d_ws, size_t ws_size,
                              hipStream_t stream) {
    const void *X = d_in[0], *W1 = d_in[1], *b1 = d_in[2], *W2 = d_in[3], *b2 = d_in[4];
    for (int i = 0; i < n_in; i++) {
        switch (in_sizes[i]) {
            case NBATCH * SEQ * DMODEL: X  = d_in[i]; break;
            case DMODEL * 3 * DMODEL:   W1 = d_in[i]; break;
            case 3 * DMODEL:            b1 = d_in[i]; break;
            case DMODEL * DMODEL:       W2 = d_in[i]; break;
            case DMODEL:                b2 = d_in[i]; break;
        }
    }
    float* out = (float*)d_out;

    int* flags = (int*)d_ws;
    unsigned short* base = (unsigned short*)d_ws + 64;
    unsigned short* Wt1 = base;                                 // [2304][768]
    unsigned short* Wt2 = Wt1 + (size_t)2304 * 768;             // [768][768]

    const size_t headElems = (size_t)NHEAD * SEQ * HD;          // 1.57M / batch
    const size_t xElems = (size_t)NBATCH * SEQ * DMODEL;        // 6.29M
    const size_t fixedElems = 64 + (size_t)2304 * 768 + (size_t)768 * 768;
    const size_t mergedNeed = (fixedElems + xElems + 4 * NBATCH * headElems) * 2 + 1024;
    const bool merged = ws_size >= mergedNeed;

    detect_k<<<1, 320, 0, stream>>>(
        (const unsigned short*)X, (const unsigned short*)W1,
        (const unsigned short*)b1, (const unsigned short*)W2,
        (const unsigned short*)b2, flags);

    if (merged) {
        unsigned short* Xb  = Wt2 + (size_t)768 * 768;          // [8192][768] bf16
        unsigned short* Qw  = Xb + xElems;
        unsigned short* Kw  = Qw + (size_t)NBATCH * headElems;
        unsigned short* Vtw = Kw + (size_t)NBATCH * headElems;
        unsigned short* Aw  = Vtw + (size_t)NBATCH * headElems;

        const int n8 = (int)(xElems / 8);                       // 786432
        const int cvtBlocks = (n8 + 255) / 256;                 // 3072
        prep<<<cvtBlocks + 432 + 144, 256, 0, stream>>>(
            (const float*)X, (const unsigned short*)X, Xb, n8, cvtBlocks,
            (const float*)W1, (const unsigned short*)W1, Wt1,
            (const float*)W2, (const unsigned short*)W2, Wt2, flags);

        gemm_bt<<<dim3(2304 / 128, NBATCH * SEQ / 128), 256, 0, stream>>>(
            nullptr, Xb, Wt1,
            (const float*)b1, (const unsigned short*)b1,
            DMODEL, 0, flags, -1, 2, Qw, Kw, Vtw, nullptr);

        flash_attn<<<dim3(NHEAD, 16, NBATCH), 256, 0, stream>>>(Qw, Kw, Vtw, Aw);

        gemm_bt<<<dim3(768 / 128, NBATCH * SEQ / 128), 256, 0, stream>>>(
            nullptr, Aw, Wt2,
            (const float*)b2, (const unsigned short*)b2,
            DMODEL, 1, flags, -1, 4, nullptr, nullptr, nullptr, out);
    } else {
        unsigned short* Qw  = Wt2 + (size_t)768 * 768;
        unsigned short* Kw  = Qw + headElems;
        unsigned short* Vtw = Kw + headElems;
        unsigned short* Aw  = Vtw + headElems;

        prep<<<432 + 144, 256, 0, stream>>>(
            nullptr, nullptr, nullptr, 0, 0,
            (const float*)W1, (const unsigned short*)W1, Wt1,
            (const float*)W2, (const unsigned short*)W2, Wt2, flags);

        for (int batch = 0; batch < NBATCH; ++batch) {
            const size_t xoff = (size_t)batch * SEQ * DMODEL;

            gemm_bt<<<dim3(2304 / 128, SEQ / 128), 256, 0, stream>>>(
                (const float*)X + xoff, (const unsigned short*)X + xoff, Wt1,
                (const float*)b1, (const unsigned short*)b1,
                DMODEL, 0, flags, 0, 2, Qw, Kw, Vtw, nullptr);

            flash_attn<<<dim3(NHEAD, 16, 1), 256, 0, stream>>>(Qw, Kw, Vtw, Aw);

            gemm_bt<<<dim3(768 / 128, SEQ / 128), 256, 0, stream>>>(
                nullptr, Aw, Wt2,
                (const float*)b2, (const unsigned short*)b2,
                DMODEL, 1, flags, -1, 4, nullptr, nullptr, nullptr, out + xoff);
        }
    }
}